// Round 1
// baseline (757.777 us; speedup 1.0000x reference)
//
#include <hip/hip_runtime.h>
#include <hip/hip_bf16.h>

typedef __attribute__((ext_vector_type(8))) short short8;
typedef __attribute__((ext_vector_type(4))) float f32x4;
typedef __attribute__((ext_vector_type(4))) unsigned short u16x4;
typedef __attribute__((ext_vector_type(8))) unsigned short u16x8;

#define INV_SCALE 0.03125f  // 1/sqrt(D=1024), per reference (model dim, not head dim)

__device__ __forceinline__ unsigned short f2bf(float f) {
  // round-to-nearest-even fp32 -> bf16
  unsigned u = __float_as_uint(f);
  u += 0x7fffu + ((u >> 16) & 1u);
  return (unsigned short)(u >> 16);
}

// ---------------------------------------------------------------------------
// QKV projection: out_z[m,n] = sum_k X[m,k] * Wz[n,k]  (y = x @ W^T)
// X: [4096,1024] fp32, Wz: [1024,1024] fp32 -> ws bf16 [3][4096][1024]
// grid (32 mtiles, 8 ntiles, 3 mats), block 512 (8 waves)
// ---------------------------------------------------------------------------
__global__ __launch_bounds__(512) void qkv_proj(
    const float* __restrict__ X, const float* __restrict__ Wq,
    const float* __restrict__ Wk, const float* __restrict__ Wv,
    unsigned short* __restrict__ ws) {
  const int mt = blockIdx.x, nt = blockIdx.y, z = blockIdx.z;
  const float* __restrict__ W = (z == 0) ? Wq : (z == 1) ? Wk : Wv;
  unsigned short* __restrict__ out = ws + (size_t)z * 4096 * 1024;

  // +8 pad: row stride 144B -> fragment reads land 2 lanes/bank (free)
  __shared__ unsigned short As[128][72];
  __shared__ unsigned short Bs[128][72];

  const int tid = threadIdx.x;
  const int wave = tid >> 6, lane = tid & 63;
  const int lq = lane & 15, lg = lane >> 4;

  f32x4 acc[8] = {};  // wave: rows [wave*16,+16) x all 128 cols (8 subtiles)

  for (int kt = 0; kt < 1024; kt += 64) {
    {
      const int row0 = tid >> 4;        // 0..31
      const int col  = (tid & 15) * 4;  // 0..60
#pragma unroll
      for (int i = 0; i < 4; ++i) {
        const int row = row0 + 32 * i;
        float4 a = *(const float4*)(X + (size_t)(mt * 128 + row) * 1024 + kt + col);
        float4 b = *(const float4*)(W + (size_t)(nt * 128 + row) * 1024 + kt + col);
        u16x4 ah = {f2bf(a.x), f2bf(a.y), f2bf(a.z), f2bf(a.w)};
        u16x4 bh = {f2bf(b.x), f2bf(b.y), f2bf(b.z), f2bf(b.w)};
        *(u16x4*)&As[row][col] = ah;
        *(u16x4*)&Bs[row][col] = bh;
      }
    }
    __syncthreads();
#pragma unroll
    for (int ks = 0; ks < 2; ++ks) {
      short8 af = *(const short8*)&As[wave * 16 + lq][ks * 32 + lg * 8];
#pragma unroll
      for (int n = 0; n < 8; ++n) {
        short8 bf = *(const short8*)&Bs[n * 16 + lq][ks * 32 + lg * 8];
        acc[n] = __builtin_amdgcn_mfma_f32_16x16x32_bf16(af, bf, acc[n], 0, 0, 0);
      }
    }
    __syncthreads();
  }
  // epilogue: C/D map col=lane&15, row=(lane>>4)*4+reg  (m89-verified)
#pragma unroll
  for (int n = 0; n < 8; ++n)
#pragma unroll
    for (int r = 0; r < 4; ++r) {
      const int row = mt * 128 + wave * 16 + lg * 4 + r;
      const int col = nt * 128 + n * 16 + lq;
      out[(size_t)row * 1024 + col] = f2bf(acc[n][r]);
    }
}

// ---------------------------------------------------------------------------
// Attention per (b,h): Q',K',V' = contiguous [2048,64] bf16 blocks of ws.
// Two-pass online softmax: pass1 stats (m,l), pass2 recompute S, write
// P=softmax to sim_score (fp32), accumulate O = P @ V'.
// grid (16 qblocks, 32 bh), block 512 (8 waves; wave owns 16 q-rows)
// ---------------------------------------------------------------------------
__global__ __launch_bounds__(512) void mha_attn(
    const unsigned short* __restrict__ ws, float* __restrict__ out) {
  const int qb = blockIdx.x;
  const int bh = blockIdx.y;
  const int b = bh >> 4, h = bh & 15;

  const unsigned short* __restrict__ Qg = ws + ((size_t)b * 2048 + h * 128) * 1024;
  const unsigned short* __restrict__ Kg = Qg + (size_t)4096 * 1024;
  const unsigned short* __restrict__ Vg = Qg + (size_t)2 * 4096 * 1024;

  float* __restrict__ simout =
      out + (size_t)4194304 + ((size_t)bh * 2048 + (size_t)qb * 128) * 2048;
  float* __restrict__ attnout = out + (size_t)b * 2048 * 1024 + h * 64;

  __shared__ unsigned short Ks[128][72];    // K-tile, row-major, +8 pad
  __shared__ unsigned short VTs[64][136];   // V-tile transposed [d][k], +8 pad
  __shared__ unsigned short Ps[8][16][136]; // per-wave P strip [16 q][128 k]

  const int tid = threadIdx.x;
  const int wave = tid >> 6, lane = tid & 63;
  const int lq = lane & 15, lg = lane >> 4;

  // Q fragments for this wave's 16-row strip (row = l&15, k = (l>>4)*8+j)
  short8 qf[2];
  {
    const unsigned short* qrow = Qg + (size_t)(qb * 128 + wave * 16 + lq) * 64;
    qf[0] = *(const short8*)(qrow + lg * 8);
    qf[1] = *(const short8*)(qrow + 32 + lg * 8);
  }

  float m[4], l[4];
#pragma unroll
  for (int r = 0; r < 4; ++r) { m[r] = -1e30f; l[r] = 0.f; }

  // ---------------- pass 1: softmax stats ----------------
  for (int kt = 0; kt < 16; ++kt) {
#pragma unroll
    for (int i = 0; i < 2; ++i) {
      const int slot = tid + 512 * i;
      const int row = slot >> 3, cg = (slot & 7) * 8;
      u16x8 v = *(const u16x8*)(Kg + (size_t)(kt * 128 + row) * 64 + cg);
      *(u16x8*)&Ks[row][cg] = v;
    }
    __syncthreads();
    f32x4 acc[8] = {};
#pragma unroll
    for (int ks = 0; ks < 2; ++ks)
#pragma unroll
      for (int n = 0; n < 8; ++n) {
        short8 kf = *(const short8*)&Ks[n * 16 + lq][ks * 32 + lg * 8];
        acc[n] = __builtin_amdgcn_mfma_f32_16x16x32_bf16(qf[ks], kf, acc[n], 0, 0, 0);
      }
#pragma unroll
    for (int r = 0; r < 4; ++r) {
      float v = acc[0][r];
#pragma unroll
      for (int n = 1; n < 8; ++n) v = fmaxf(v, acc[n][r]);
#pragma unroll
      for (int off = 1; off < 16; off <<= 1) v = fmaxf(v, __shfl_xor(v, off));
      const float mn = fmaxf(m[r], v * INV_SCALE);
      float s = 0.f;
#pragma unroll
      for (int n = 0; n < 8; ++n) s += __expf(acc[n][r] * INV_SCALE - mn);
#pragma unroll
      for (int off = 1; off < 16; off <<= 1) s += __shfl_xor(s, off);
      l[r] = l[r] * __expf(m[r] - mn) + s;
      m[r] = mn;
    }
    __syncthreads();
  }

  float linv[4];
#pragma unroll
  for (int r = 0; r < 4; ++r) linv[r] = 1.0f / l[r];

  f32x4 oacc[4] = {};

  // ---------------- pass 2: P write + PV ----------------
  for (int kt = 0; kt < 16; ++kt) {
#pragma unroll
    for (int i = 0; i < 2; ++i) {
      const int slot = tid + 512 * i;
      const int row = slot >> 3, cg = (slot & 7) * 8;
      u16x8 v = *(const u16x8*)(Kg + (size_t)(kt * 128 + row) * 64 + cg);
      *(u16x8*)&Ks[row][cg] = v;
    }
    {
      // V-tile transpose-stage: pack rows k0,k0+1 per dword write
      const int k0 = (tid >> 3) * 2, cg = (tid & 7) * 8;
      u16x8 va = *(const u16x8*)(Vg + (size_t)(kt * 128 + k0) * 64 + cg);
      u16x8 vb = *(const u16x8*)(Vg + (size_t)(kt * 128 + k0 + 1) * 64 + cg);
#pragma unroll
      for (int j = 0; j < 8; ++j) {
        unsigned val = (unsigned)va[j] | ((unsigned)vb[j] << 16);
        *(unsigned*)&VTs[cg + j][k0] = val;
      }
    }
    __syncthreads();
    f32x4 acc[8] = {};
#pragma unroll
    for (int ks = 0; ks < 2; ++ks)
#pragma unroll
      for (int n = 0; n < 8; ++n) {
        short8 kf = *(const short8*)&Ks[n * 16 + lq][ks * 32 + lg * 8];
        acc[n] = __builtin_amdgcn_mfma_f32_16x16x32_bf16(qf[ks], kf, acc[n], 0, 0, 0);
      }
    // P = exp(s - m)/l ; write sim_score + stash bf16 copy in own LDS strip
#pragma unroll
    for (int n = 0; n < 8; ++n)
#pragma unroll
      for (int r = 0; r < 4; ++r) {
        const float p = __expf(acc[n][r] * INV_SCALE - m[r]) * linv[r];
        simout[(size_t)(wave * 16 + lg * 4 + r) * 2048 + kt * 128 + n * 16 + lq] = p;
        Ps[wave][lg * 4 + r][n * 16 + lq] = f2bf(p);
      }
    // PV: O[q,d] += sum_k P[q,k] V[k,d]; B-frag from VTs (k-contiguous)
#pragma unroll
    for (int d = 0; d < 4; ++d)
#pragma unroll
      for (int ks = 0; ks < 4; ++ks) {
        short8 pf = *(const short8*)&Ps[wave][lq][ks * 32 + lg * 8];
        short8 vf = *(const short8*)&VTs[d * 16 + lq][ks * 32 + lg * 8];
        oacc[d] = __builtin_amdgcn_mfma_f32_16x16x32_bf16(pf, vf, oacc[d], 0, 0, 0);
      }
    __syncthreads();
  }
  // self_attn[b, s', h*64+d]  (transpose(0,2,1,3).reshape)
#pragma unroll
  for (int d = 0; d < 4; ++d)
#pragma unroll
    for (int r = 0; r < 4; ++r) {
      attnout[(size_t)(qb * 128 + wave * 16 + lg * 4 + r) * 1024 + d * 16 + lq] =
          oacc[d][r];
    }
}

extern "C" void kernel_launch(void* const* d_in, const int* in_sizes, int n_in,
                              void* d_out, int out_size, void* d_ws, size_t ws_size,
                              hipStream_t stream) {
  const float* X  = (const float*)d_in[0];
  const float* Wq = (const float*)d_in[1];
  const float* Wk = (const float*)d_in[2];
  const float* Wv = (const float*)d_in[3];
  unsigned short* ws = (unsigned short*)d_ws;  // needs 3*4096*1024*2 = 24 MiB
  float* out = (float*)d_out;

  qkv_proj<<<dim3(32, 8, 3), 512, 0, stream>>>(X, Wq, Wk, Wv, ws);
  mha_attn<<<dim3(16, 32), 512, 0, stream>>>(ws, out);
}

// Round 2
// 704.774 us; speedup vs baseline: 1.0752x; 1.0752x over previous
//
#include <hip/hip_runtime.h>
#include <hip/hip_bf16.h>

typedef __attribute__((ext_vector_type(8))) short short8;
typedef __attribute__((ext_vector_type(4))) float f32x4;
typedef __attribute__((ext_vector_type(8))) unsigned short u16x8;

#define LOG2E 1.4426950408889634f

__device__ __forceinline__ unsigned pk2(float a, float b) {
  // packed fp32x2 -> bf16x2 (v_cvt_pk_bf16_f32), low word = a
  __hip_bfloat162 h = __float22bfloat162_rn(float2{a, b});
  return *reinterpret_cast<unsigned*>(&h);
}

__device__ __forceinline__ unsigned short f2bf(float f) {
  __hip_bfloat16 h = __float2bfloat16(f);
  return *reinterpret_cast<unsigned short*>(&h);
}

// ---------------------------------------------------------------------------
// QKV projection: out_z[m,n] = sum_k X[m,k] * Wz[n,k]   (y = x @ W^T)
// X: [4096,1024] fp32, Wz: [1024,1024] fp32 -> ws bf16 [3][4096][1024]
// Q (z==0) pre-scaled by 1/32 (exact in bf16) so attn logits need no scale.
// grid (32 mt, 8 nt, 3 z), block 256 (4 waves 2x2, wave owns 64x64)
// ---------------------------------------------------------------------------
__global__ __launch_bounds__(256, 3) void qkv_proj(
    const float* __restrict__ X, const float* __restrict__ Wq,
    const float* __restrict__ Wk, const float* __restrict__ Wv,
    unsigned short* __restrict__ ws) {
  const int mt = blockIdx.x, nt = blockIdx.y, z = blockIdx.z;
  const float* __restrict__ W = (z == 0) ? Wq : (z == 1) ? Wk : Wv;
  unsigned short* __restrict__ out = ws + (size_t)z * 4096 * 1024;
  const float osc = (z == 0) ? 0.03125f : 1.0f;

  __shared__ unsigned short As[128][72];  // +8 pad, 16B-aligned rows
  __shared__ unsigned short Bs[128][72];

  const int tid = threadIdx.x;
  const int wave = tid >> 6, lane = tid & 63;
  const int lq = lane & 15, lg = lane >> 4;
  const int wr = wave >> 1, wc = wave & 1;

  f32x4 acc[4][4] = {};

  const int srow = tid >> 4;        // 0..15
  const int sc4 = (tid & 15) * 4;   // float col 0..60

  for (int kt = 0; kt < 1024; kt += 64) {
#pragma unroll
    for (int i = 0; i < 8; ++i) {
      const int row = srow + 16 * i;
      float4 a = *(const float4*)(X + (size_t)(mt * 128 + row) * 1024 + kt + sc4);
      float4 b = *(const float4*)(W + (size_t)(nt * 128 + row) * 1024 + kt + sc4);
      *(uint2*)&As[row][sc4] = make_uint2(pk2(a.x, a.y), pk2(a.z, a.w));
      *(uint2*)&Bs[row][sc4] = make_uint2(pk2(b.x, b.y), pk2(b.z, b.w));
    }
    __syncthreads();
#pragma unroll
    for (int ks = 0; ks < 2; ++ks) {
      short8 af[4], bf[4];
#pragma unroll
      for (int i = 0; i < 4; ++i) {
        af[i] = *(const short8*)&As[wr * 64 + i * 16 + lq][ks * 32 + lg * 8];
        bf[i] = *(const short8*)&Bs[wc * 64 + i * 16 + lq][ks * 32 + lg * 8];
      }
#pragma unroll
      for (int i = 0; i < 4; ++i)
#pragma unroll
        for (int j = 0; j < 4; ++j)
          acc[i][j] = __builtin_amdgcn_mfma_f32_16x16x32_bf16(af[i], bf[j], acc[i][j], 0, 0, 0);
    }
    __syncthreads();
  }
  // C/D: col = lane&15, row = (lane>>4)*4 + r
#pragma unroll
  for (int i = 0; i < 4; ++i)
#pragma unroll
    for (int j = 0; j < 4; ++j)
#pragma unroll
      for (int r = 0; r < 4; ++r) {
        const int row = mt * 128 + wr * 64 + i * 16 + lg * 4 + r;
        const int col = nt * 128 + wc * 64 + j * 16 + lq;
        out[(size_t)row * 1024 + col] = f2bf(acc[i][j][r] * osc);
      }
}

// ---------------------------------------------------------------------------
// Attention per (b,h): Q',K',V' are contiguous [2048,64] bf16 blocks of ws
// (the reference's seq-splitting .view makes each head's operand contiguous).
// Swapped QK^T: acc = mfma(K,Q) -> D[k][q]; lane lq owns q-row lq, regs hold
// 4 consecutive k. Two-pass: pass1 per-lane stats, pass2 recompute + float4
// P stores + b64 bf16 stash + PV.
// grid (16 qb, 32 bh), block 512 (8 waves; wave owns 16 q-rows)
// ---------------------------------------------------------------------------
__global__ __launch_bounds__(512, 4) void mha_attn(
    const unsigned short* __restrict__ ws, float* __restrict__ out) {
  const int qb = blockIdx.x;
  const int bh = blockIdx.y;
  const int b = bh >> 4, h = bh & 15;

  const unsigned short* __restrict__ Qg = ws + ((size_t)b * 2048 + h * 128) * 1024;
  const unsigned short* __restrict__ Kg = Qg + (size_t)4096 * 1024;
  const unsigned short* __restrict__ Vg = Qg + (size_t)2 * 4096 * 1024;

  float* __restrict__ simout =
      out + (size_t)4194304 + ((size_t)bh * 2048 + (size_t)qb * 128) * 2048;
  float* __restrict__ attnout = out + (size_t)b * 2048 * 1024 + h * 64;

  __shared__ unsigned short Ks[128][72];     // +8 pad
  __shared__ unsigned short VTs[64][136];    // V^T [d][k], +8 pad (16B rows)
  __shared__ unsigned short Ps[8][16][136];  // per-wave P strip [q][k]

  const int tid = threadIdx.x;
  const int wave = tid >> 6, lane = tid & 63;
  const int lq = lane & 15, lg = lane >> 4;

  short8 qf[2];  // B-operand frags: col=l&15 -> q within wave strip
  {
    const unsigned short* qrow = Qg + (size_t)(qb * 128 + wave * 16 + lq) * 64;
    qf[0] = *(const short8*)(qrow + lg * 8);
    qf[1] = *(const short8*)(qrow + 32 + lg * 8);
  }

  float m = -1e30f, l = 0.f;  // per-lane: q = wave*16 + lq

  // ---------------- pass 1: softmax stats ----------------
  for (int kt = 0; kt < 16; ++kt) {
#pragma unroll
    for (int i = 0; i < 2; ++i) {
      const int slot = tid + 512 * i;
      const int row = slot >> 3, cg = (slot & 7) * 8;
      *(u16x8*)&Ks[row][cg] = *(const u16x8*)(Kg + (size_t)(kt * 128 + row) * 64 + cg);
    }
    __syncthreads();
    f32x4 acc[8] = {};
#pragma unroll
    for (int ks = 0; ks < 2; ++ks)
#pragma unroll
      for (int n = 0; n < 8; ++n) {
        short8 kf = *(const short8*)&Ks[n * 16 + lq][ks * 32 + lg * 8];
        acc[n] = __builtin_amdgcn_mfma_f32_16x16x32_bf16(kf, qf[ks], acc[n], 0, 0, 0);
      }
    float mx = acc[0][0];
#pragma unroll
    for (int n = 0; n < 8; ++n)
#pragma unroll
      for (int r = 0; r < 4; ++r) mx = fmaxf(mx, acc[n][r]);
    mx = fmaxf(mx, __shfl_xor(mx, 16));
    mx = fmaxf(mx, __shfl_xor(mx, 32));
    const float mn = fmaxf(m, mx);
    const float m2 = mn * LOG2E;
    float s = 0.f;
#pragma unroll
    for (int n = 0; n < 8; ++n)
#pragma unroll
      for (int r = 0; r < 4; ++r)
        s += __builtin_amdgcn_exp2f(acc[n][r] * LOG2E - m2);
    s += __shfl_xor(s, 16);
    s += __shfl_xor(s, 32);
    l = l * __builtin_amdgcn_exp2f(m * LOG2E - m2) + s;
    m = mn;
    __syncthreads();
  }

  const float m2f = m * LOG2E;
  const float linv = 1.0f / l;

  f32x4 oacc[4] = {};

  // ---------------- pass 2: P write + PV ----------------
  for (int kt = 0; kt < 16; ++kt) {
#pragma unroll
    for (int i = 0; i < 2; ++i) {
      const int slot = tid + 512 * i;
      const int row = slot >> 3, cg = (slot & 7) * 8;
      *(u16x8*)&Ks[row][cg] = *(const u16x8*)(Kg + (size_t)(kt * 128 + row) * 64 + cg);
    }
    {
      // stage V transposed: [k][d] -> VTs[d][k], pack 2 k per dword
      const int k0 = (tid >> 3) * 2, cg = (tid & 7) * 8;
      u16x8 va = *(const u16x8*)(Vg + (size_t)(kt * 128 + k0) * 64 + cg);
      u16x8 vb = *(const u16x8*)(Vg + (size_t)(kt * 128 + k0 + 1) * 64 + cg);
#pragma unroll
      for (int j = 0; j < 8; ++j) {
        unsigned val = (unsigned)(unsigned short)va[j] | ((unsigned)(unsigned short)vb[j] << 16);
        *(unsigned*)&VTs[cg + j][k0] = val;
      }
    }
    __syncthreads();
    f32x4 acc[8] = {};
#pragma unroll
    for (int ks = 0; ks < 2; ++ks)
#pragma unroll
      for (int n = 0; n < 8; ++n) {
        short8 kf = *(const short8*)&Ks[n * 16 + lq][ks * 32 + lg * 8];
        acc[n] = __builtin_amdgcn_mfma_f32_16x16x32_bf16(kf, qf[ks], acc[n], 0, 0, 0);
      }
    // lane: q = wave*16+lq, k = kt*128 + n*16 + lg*4 + r  (4 consecutive k)
    float* simrow = simout + (size_t)(wave * 16 + lq) * 2048 + kt * 128 + lg * 4;
#pragma unroll
    for (int n = 0; n < 8; ++n) {
      float4 p;
      p.x = __builtin_amdgcn_exp2f(acc[n][0] * LOG2E - m2f) * linv;
      p.y = __builtin_amdgcn_exp2f(acc[n][1] * LOG2E - m2f) * linv;
      p.z = __builtin_amdgcn_exp2f(acc[n][2] * LOG2E - m2f) * linv;
      p.w = __builtin_amdgcn_exp2f(acc[n][3] * LOG2E - m2f) * linv;
      *(float4*)(simrow + n * 16) = p;
      *(uint2*)&Ps[wave][lq][n * 16 + lg * 4] = make_uint2(pk2(p.x, p.y), pk2(p.z, p.w));
    }
    // PV: O[q,d] += P[q,k] V[k,d]; pf hoisted out of d-loop (wave-private Ps)
#pragma unroll
    for (int ks = 0; ks < 4; ++ks) {
      short8 pf = *(const short8*)&Ps[wave][lq][ks * 32 + lg * 8];
#pragma unroll
      for (int d = 0; d < 4; ++d) {
        short8 vf = *(const short8*)&VTs[d * 16 + lq][ks * 32 + lg * 8];
        oacc[d] = __builtin_amdgcn_mfma_f32_16x16x32_bf16(pf, vf, oacc[d], 0, 0, 0);
      }
    }
    __syncthreads();
  }
  // O: D rows = q (lg*4+r), cols = d (lq); P was normalized -> no fixup
#pragma unroll
  for (int d = 0; d < 4; ++d)
#pragma unroll
    for (int r = 0; r < 4; ++r) {
      attnout[(size_t)(qb * 128 + wave * 16 + lg * 4 + r) * 1024 + d * 16 + lq] =
          oacc[d][r];
    }
}

extern "C" void kernel_launch(void* const* d_in, const int* in_sizes, int n_in,
                              void* d_out, int out_size, void* d_ws, size_t ws_size,
                              hipStream_t stream) {
  const float* X  = (const float*)d_in[0];
  const float* Wq = (const float*)d_in[1];
  const float* Wk = (const float*)d_in[2];
  const float* Wv = (const float*)d_in[3];
  unsigned short* ws = (unsigned short*)d_ws;  // 3*4096*1024*2 = 24 MiB
  float* out = (float*)d_out;

  qkv_proj<<<dim3(32, 8, 3), 256, 0, stream>>>(X, Wq, Wk, Wv, ws);
  mha_attn<<<dim3(16, 32), 512, 0, stream>>>(ws, out);
}